// Round 2
// baseline (162.866 us; speedup 1.0000x reference)
//
#include <hip/hip_runtime.h>
#include <hip/hip_bf16.h>
#include <cstdint>

#define HD 128

typedef __attribute__((ext_vector_type(8))) short short8;
typedef __attribute__((ext_vector_type(4))) float f32x4;
typedef __attribute__((ext_vector_type(4))) unsigned int u32x4;

static __device__ __forceinline__ short bf16_bits(float v) {
    __hip_bfloat16 h = __float2bfloat16(v);
    return __builtin_bit_cast(short, h);
}

// ---------------------------------------------------------------------------
// Mask dtype detector: if mask was uploaded as int32/float32, every byte at
// position 4k+1 is 0; if uploaded as 1-byte bool, ~50% of them are 1.
// Writes flag (1 = bytewise) into ws. One block, trivial cost.
// ---------------------------------------------------------------------------
__global__ void detect_mask_kernel(const unsigned char* __restrict__ mask,
                                   int n_elems, int* __restrict__ flag)
{
    __shared__ int any;
    if (threadIdx.x == 0) any = 0;
    __syncthreads();
    int limit = n_elems / 4;
    if (limit > 16384) limit = 16384;
    int local = 0;
    for (int k = threadIdx.x; k < limit; k += blockDim.x)
        local |= mask[4 * k + 1];
    if (local) atomicOr(&any, 1);
    __syncthreads();
    if (threadIdx.x == 0) *flag = any;
}

// ---------------------------------------------------------------------------
// Pre-cast kernel: W{1,2,3}[d] (fp32, [j_in][m_out]) -> bf16 A-operand image in ws.
// Image for matrix s (= d*3 + layer): 128 rows (m) x 256 B. Row m holds 16
// 16-B granules; granule G = 4*kb + g (kb = K-block, g = lane group) holds
// elements jj=0..7 with logical j = 32*kb + 16*(jj>>2) + 4*g + (jj&3)
// (the K-permutation that makes MFMA D-layout == next-layer B-layout).
// Granule placed at byte (G*16) ^ ((m&7)<<4)  (bank-conflict XOR swizzle).
// ---------------------------------------------------------------------------
__global__ __launch_bounds__(256) void precast_kernel(
    const float* __restrict__ W1, const float* __restrict__ W2,
    const float* __restrict__ W3, char* __restrict__ ws)
{
    const int s = blockIdx.x;            // 0..8
    const int d = s / 3, li = s % 3;
    const float* W = (li == 0 ? W1 : li == 1 ? W2 : W3) + d * HD * HD;
    const int tid = threadIdx.x;
    const int m = tid & 127;
    const int gh = tid >> 7;             // 0/1: which half of the 16 granules
    char* dst_row = ws + s * 32768 + m * 256;
    #pragma unroll
    for (int it = 0; it < 8; ++it) {
        const int G = gh * 8 + it;
        const int kb = G >> 2, g = G & 3;
        const int j0 = kb * 32 + g * 4;
        float v[8];
        #pragma unroll
        for (int w = 0; w < 2; ++w)
            #pragma unroll
            for (int q = 0; q < 4; ++q)
                v[w * 4 + q] = W[(j0 + w * 16 + q) * HD + m];
        unsigned int p[4];
        #pragma unroll
        for (int w = 0; w < 4; ++w) {
            unsigned lo = (unsigned short)bf16_bits(v[2 * w]);
            unsigned hi = (unsigned short)bf16_bits(v[2 * w + 1]);
            p[w] = lo | (hi << 16);
        }
        const int boff = (G * 16) ^ ((m & 7) << 4);
        *reinterpret_cast<u32x4*>(dst_row + boff) = u32x4{p[0], p[1], p[2], p[3]};
    }
}

// ---------------------------------------------------------------------------
// Main fused kernel. Block = 256 thr (4 waves); wave owns 64 batch rows
// (4 c-tiles of 16). h kept entirely in registers as B-fragments (transposed
// chain); weights LDS-double-buffered, prefetched with global_load_lds.
// ---------------------------------------------------------------------------
static __device__ __forceinline__ void stage_weights(const char* __restrict__ src,
                                                     char* ldsdst, int wid, int lane)
{
    #pragma unroll
    for (int it = 0; it < 8; ++it) {
        const int c = wid * 8 + it;      // 32 chunks of 1024 B = 32 KB
        __builtin_amdgcn_global_load_lds(
            (const __attribute__((address_space(1))) void*)(src + c * 1024 + lane * 16),
            (__attribute__((address_space(3))) void*)(ldsdst + c * 1024),
            16, 0, 0);
    }
}

__global__ __launch_bounds__(256, 1) void mlp_kernel(
    const float* __restrict__ x, const void* __restrict__ maskraw,
    const int* __restrict__ mflag,
    const float* __restrict__ W0, const float* __restrict__ b0,
    const float* __restrict__ b1, const float* __restrict__ b2,
    const float* __restrict__ b3, const char* __restrict__ wsWT,
    float* __restrict__ out)
{
    __shared__ char wlds[2 * 32768];
    const int tid  = threadIdx.x;
    const int wid  = tid >> 6;
    const int lane = tid & 63;
    const int r    = lane & 15;          // batch-row within c-tile (MFMA col)
    const int g    = lane >> 4;          // lane group (MFMA row-quad / k-group)
    const int row0 = blockIdx.x * 256 + wid * 64;
    const bool bytewise = (*mflag != 0);
    const unsigned char* mask_b = (const unsigned char*)maskraw;
    const int*           mask_w = (const int*)maskraw;

    // final accumulator: out^T tiles, acc3[tm][tc][i] = out[row0+tc*16+r][tm*16+g*4+i]
    f32x4 acc3[8][4];
    #pragma unroll
    for (int tm = 0; tm < 8; ++tm)
        #pragma unroll
        for (int tc = 0; tc < 4; ++tc)
            acc3[tm][tc] = f32x4{0.f, 0.f, 0.f, 0.f};

    stage_weights(wsWT, wlds, wid, lane);      // s = 0 into buf 0

    short8 bfrag[4][4];                         // h^T fragments [kb][tc]
    f32x4  acct[8][4];                          // per-layer temp accumulator
    int cur = 0;

    for (int d = 0; d < 3; ++d) {
        // per-dim scalar inputs (L1-hot)
        float xv[4], mkf[4];
        #pragma unroll
        for (int tc = 0; tc < 4; ++tc) {
            const int row = row0 + tc * 16 + r;
            const int mi  = row * 3 + d;
            xv[tc]  = x[mi];
            mkf[tc] = (bytewise ? (mask_b[mi] != 0) : (mask_w[mi] != 0)) ? 1.0f : 0.0f;
        }

        // ---- layer 0: h0 = relu(x*W0 + b0), built directly as B-fragments ----
        const float* W0d = W0 + d * HD;
        const float* b0d = b0 + d * HD;
        #pragma unroll
        for (int kb = 0; kb < 4; ++kb) {
            const f32x4 w0a = *(const f32x4*)(W0d + kb * 32 + g * 4);
            const f32x4 w0b = *(const f32x4*)(W0d + kb * 32 + 16 + g * 4);
            const f32x4 bba = *(const f32x4*)(b0d + kb * 32 + g * 4);
            const f32x4 bbb = *(const f32x4*)(b0d + kb * 32 + 16 + g * 4);
            #pragma unroll
            for (int tc = 0; tc < 4; ++tc) {
                short8 f;
                #pragma unroll
                for (int q = 0; q < 4; ++q) {
                    const float va = fmaxf(xv[tc] * w0a[q] + bba[q], 0.f);
                    const float vb = fmaxf(xv[tc] * w0b[q] + bbb[q], 0.f);
                    f[q]     = bf16_bits(va);
                    f[4 + q] = bf16_bits(vb);
                }
                bfrag[kb][tc] = f;
            }
        }

        // ---- layers 1..3 (MFMA) ----
        #pragma unroll
        for (int li = 0; li < 3; ++li) {
            const int s = d * 3 + li;
            __syncthreads();                     // drains my stage's vmcnt, then barrier
            if (s < 8) stage_weights(wsWT + (s + 1) * 32768, wlds + (cur ^ 1) * 32768, wid, lane);
            const char* wbase = wlds + cur * 32768;

            if (li < 2) {                        // init temp acc with bias
                const float* bb = (li == 0 ? b1 : b2) + d * HD;
                #pragma unroll
                for (int tm = 0; tm < 8; ++tm) {
                    const f32x4 bv = *(const f32x4*)(bb + tm * 16 + g * 4);
                    #pragma unroll
                    for (int tc = 0; tc < 4; ++tc) acct[tm][tc] = bv;
                }
            }

            #pragma unroll
            for (int kb = 0; kb < 4; ++kb) {
                short8 afr[8];
                #pragma unroll
                for (int tm = 0; tm < 8; ++tm) {
                    const int m = tm * 16 + r;
                    const int boff = (kb * 64 + g * 16) ^ ((m & 7) << 4);
                    afr[tm] = *reinterpret_cast<const short8*>(wbase + m * 256 + boff);
                }
                #pragma unroll
                for (int tm = 0; tm < 8; ++tm)
                    #pragma unroll
                    for (int tc = 0; tc < 4; ++tc) {
                        if (li < 2)
                            acct[tm][tc] = __builtin_amdgcn_mfma_f32_16x16x32_bf16(
                                afr[tm], bfrag[kb][tc], acct[tm][tc], 0, 0, 0);
                        else
                            acc3[tm][tc] = __builtin_amdgcn_mfma_f32_16x16x32_bf16(
                                afr[tm], bfrag[kb][tc], acc3[tm][tc], 0, 0, 0);
                    }
            }

            // layer output -> next B-fragments (pure in-register: K-permutation
            // makes D layout == B layout). Mask folded into h2 before layer 3.
            if (li < 2) {
                #pragma unroll
                for (int kb = 0; kb < 4; ++kb)
                    #pragma unroll
                    for (int tc = 0; tc < 4; ++tc) {
                        short8 f;
                        #pragma unroll
                        for (int q = 0; q < 4; ++q) {
                            float va = fmaxf(acct[2 * kb][tc][q], 0.f);
                            float vb = fmaxf(acct[2 * kb + 1][tc][q], 0.f);
                            if (li == 1) { va *= mkf[tc]; vb *= mkf[tc]; }
                            f[q]     = bf16_bits(va);
                            f[4 + q] = bf16_bits(vb);
                        }
                        bfrag[kb][tc] = f;
                    }
            }
            cur ^= 1;
        }
    }

    // ---- epilogue: + sum_d mask_d * b3_d, store fp32 float4 ----
    #pragma unroll
    for (int tc = 0; tc < 4; ++tc) {
        const int row = row0 + tc * 16 + r;
        float mk[3];
        #pragma unroll
        for (int dd = 0; dd < 3; ++dd) {
            const int mi = row * 3 + dd;
            mk[dd] = (bytewise ? (mask_b[mi] != 0) : (mask_w[mi] != 0)) ? 1.f : 0.f;
        }
        float* orow = out + (long)row * HD;
        #pragma unroll
        for (int tm = 0; tm < 8; ++tm) {
            const f32x4 ba  = *(const f32x4*)(b3 + 0 * HD + tm * 16 + g * 4);
            const f32x4 bbv = *(const f32x4*)(b3 + 1 * HD + tm * 16 + g * 4);
            const f32x4 bc  = *(const f32x4*)(b3 + 2 * HD + tm * 16 + g * 4);
            f32x4 o = acc3[tm][tc];
            #pragma unroll
            for (int q = 0; q < 4; ++q)
                o[q] += mk[0] * ba[q] + mk[1] * bbv[q] + mk[2] * bc[q];
            *reinterpret_cast<f32x4*>(orow + tm * 16 + g * 4) = o;
        }
    }
}

extern "C" void kernel_launch(void* const* d_in, const int* in_sizes, int n_in,
                              void* d_out, int out_size, void* d_ws, size_t ws_size,
                              hipStream_t stream) {
    const float* x  = (const float*)d_in[0];
    const unsigned char* mask = (const unsigned char*)d_in[1];
    const float* W0 = (const float*)d_in[2];
    const float* b0 = (const float*)d_in[3];
    const float* W1 = (const float*)d_in[4];
    const float* b1 = (const float*)d_in[5];
    const float* W2 = (const float*)d_in[6];
    const float* b2 = (const float*)d_in[7];
    const float* W3 = (const float*)d_in[8];
    const float* b3 = (const float*)d_in[9];
    float* out = (float*)d_out;
    char* ws = (char*)d_ws;               // weights: 9*32768 B, flag at +294912
    int* mflag = (int*)(ws + 9 * 32768);
    const int n_mask = in_sizes[1];       // N*D elements

    hipLaunchKernelGGL(detect_mask_kernel, dim3(1), dim3(256), 0, stream,
                       mask, n_mask, mflag);
    hipLaunchKernelGGL(precast_kernel, dim3(9), dim3(256), 0, stream, W1, W2, W3, ws);
    hipLaunchKernelGGL(mlp_kernel, dim3(512), dim3(256), 0, stream,
                       x, (const void*)mask, mflag, W0, b0, b1, b2, b3, ws, out);
}

// Round 5
// 143.545 us; speedup vs baseline: 1.1346x; 1.1346x over previous
//
#include <hip/hip_runtime.h>
#include <hip/hip_bf16.h>
#include <cstdint>

#define HD 128

typedef __attribute__((ext_vector_type(8))) short short8;
typedef __attribute__((ext_vector_type(4))) float f32x4;
typedef __attribute__((ext_vector_type(4))) unsigned int u32x4;

static __device__ __forceinline__ short bf16_bits(float v) {
    __hip_bfloat16 h = __float2bfloat16(v);
    return __builtin_bit_cast(short, h);
}

// ---------------------------------------------------------------------------
// Mask dtype detector: if mask was uploaded as int32/float32, every byte at
// position 4k+1 is 0; if uploaded as 1-byte bool, ~50% of sampled bytes are 1.
// ---------------------------------------------------------------------------
__global__ void detect_mask_kernel(const unsigned char* __restrict__ mask,
                                   int n_elems, int* __restrict__ flag)
{
    __shared__ int any;
    if (threadIdx.x == 0) any = 0;
    __syncthreads();
    int limit = n_elems / 4;
    if (limit > 4096) limit = 4096;
    int local = 0;
    for (int k = threadIdx.x; k < limit; k += blockDim.x)
        local |= mask[4 * k + 1];
    if (local) atomicOr(&any, 1);
    __syncthreads();
    if (threadIdx.x == 0) *flag = any;
}

// ---------------------------------------------------------------------------
// Pre-cast: W{1,2,3}[d] (fp32, [j_in][m_out]) -> bf16 A-operand image in ws.
// Image s (= d*3+layer): 32 granule-pairs p = kb*8+tm, each a contiguous
// 1024-B block; lane l (= g*16 + r) owns bytes p*1024 + l*16 .. +15, holding
// 8 bf16 of row m = tm*16 + r with logical input index
// j = 32*kb + 16*(jj>>2) + 4*g + (jj&3)   (K-permutation: MFMA D == next B).
// Lane-ordered & contiguous => conflict-free ds_read_b128 AND linear
// global_load_lds staging.  Grid (9, 8): block = one s x 4 pairs.
// ---------------------------------------------------------------------------
__global__ __launch_bounds__(256) void precast_kernel(
    const float* __restrict__ W1, const float* __restrict__ W2,
    const float* __restrict__ W3, char* __restrict__ ws)
{
    const int s = blockIdx.x;            // 0..8
    const int d = s / 3, li = s % 3;
    const float* W = (li == 0 ? W1 : li == 1 ? W2 : W3) + d * HD * HD;
    const int t = threadIdx.x;
    const int p = blockIdx.y * 4 + (t >> 6);   // granule pair 0..31
    const int l = t & 63;
    const int kb = p >> 3, tm = p & 7;
    const int g = l >> 4;
    const int m = tm * 16 + (l & 15);
    const int jbase = 32 * kb + 4 * g;
    unsigned int pk[4];
    #pragma unroll
    for (int w = 0; w < 4; ++w) {
        const int j0 = jbase + (w >> 1) * 16 + (w & 1) * 2;   // jj = 2w
        const float a = W[j0 * HD + m];
        const float b = W[(j0 + 1) * HD + m];
        pk[w] = (unsigned short)bf16_bits(a) |
                ((unsigned)(unsigned short)bf16_bits(b) << 16);
    }
    *reinterpret_cast<u32x4*>(ws + s * 32768 + p * 1024 + l * 16) =
        u32x4{pk[0], pk[1], pk[2], pk[3]};
}

// ---------------------------------------------------------------------------
// Main fused kernel. Block = 256 thr (4 waves); wave owns 32 batch rows
// (tc = 2 c-tiles of 16). Register budget ~215 => __launch_bounds__(256,2)
// forces 2 waves/SIMD (round-2 failure was AGPR+VGPR ~488 -> 1 wave/SIMD).
// Weights LDS-double-buffered via global_load_lds; h stays in registers.
// ---------------------------------------------------------------------------
static __device__ __forceinline__ void stage_weights(const char* __restrict__ src,
                                                     char* ldsdst, int wid, int lane)
{
    #pragma unroll
    for (int it = 0; it < 8; ++it) {
        const int c = wid * 8 + it;      // 32 chunks of 1024 B = 32 KB
        __builtin_amdgcn_global_load_lds(
            (const __attribute__((address_space(1))) void*)(src + c * 1024 + lane * 16),
            (__attribute__((address_space(3))) void*)(ldsdst + c * 1024),
            16, 0, 0);
    }
}

__global__ __launch_bounds__(256, 2) void mlp_kernel(
    const float* __restrict__ x, const void* __restrict__ maskraw,
    const int* __restrict__ mflag,
    const float* __restrict__ W0, const float* __restrict__ b0,
    const float* __restrict__ b1, const float* __restrict__ b2,
    const float* __restrict__ b3, const char* __restrict__ wsWT,
    float* __restrict__ out)
{
    __shared__ char wlds[2 * 32768];
    const int tid  = threadIdx.x;
    const int wid  = tid >> 6;
    const int lane = tid & 63;
    const int r    = lane & 15;          // batch-row within c-tile (MFMA col)
    const int g    = lane >> 4;          // lane group (MFMA row-quad / k-group)
    const int row0 = blockIdx.x * 128 + wid * 32;
    const bool bytewise = (*mflag != 0);
    const unsigned char* mask_b = (const unsigned char*)maskraw;
    const int*           mask_w = (const int*)maskraw;

    // acc3[tm][tc][i] = out[row0+tc*16+r][tm*16+g*4+i]
    f32x4 acc3[8][2];
    #pragma unroll
    for (int tm = 0; tm < 8; ++tm)
        #pragma unroll
        for (int tc = 0; tc < 2; ++tc)
            acc3[tm][tc] = f32x4{0.f, 0.f, 0.f, 0.f};

    stage_weights(wsWT, wlds, wid, lane);      // s = 0 into buf 0

    short8 bfrag[4][2];                         // h^T fragments [kb][tc]
    f32x4  acct[8][2];                          // per-layer temp accumulator
    int cur = 0;

    for (int d = 0; d < 3; ++d) {
        float xv[2], mkf[2];
        #pragma unroll
        for (int tc = 0; tc < 2; ++tc) {
            const int mi = (row0 + tc * 16 + r) * 3 + d;
            xv[tc]  = x[mi];
            mkf[tc] = (bytewise ? (mask_b[mi] != 0) : (mask_w[mi] != 0)) ? 1.0f : 0.0f;
        }

        // ---- layer 0: h0 = relu(x*W0 + b0) directly as B-fragments ----
        const float* W0d = W0 + d * HD;
        const float* b0d = b0 + d * HD;
        #pragma unroll
        for (int kb = 0; kb < 4; ++kb) {
            const f32x4 w0a = *(const f32x4*)(W0d + kb * 32 + g * 4);
            const f32x4 w0b = *(const f32x4*)(W0d + kb * 32 + 16 + g * 4);
            const f32x4 bba = *(const f32x4*)(b0d + kb * 32 + g * 4);
            const f32x4 bbb = *(const f32x4*)(b0d + kb * 32 + 16 + g * 4);
            #pragma unroll
            for (int tc = 0; tc < 2; ++tc) {
                short8 f;
                #pragma unroll
                for (int q = 0; q < 4; ++q) {
                    const float va = fmaxf(xv[tc] * w0a[q] + bba[q], 0.f);
                    const float vb = fmaxf(xv[tc] * w0b[q] + bbb[q], 0.f);
                    f[q]     = bf16_bits(va);
                    f[4 + q] = bf16_bits(vb);
                }
                bfrag[kb][tc] = f;
            }
        }

        // ---- layers 1..3 (MFMA) ----
        #pragma unroll
        for (int li = 0; li < 3; ++li) {
            const int s = d * 3 + li;
            __syncthreads();                     // drains stage vmcnt, then barrier
            if (s < 8) stage_weights(wsWT + (s + 1) * 32768, wlds + (cur ^ 1) * 32768, wid, lane);
            const char* wbase = wlds + cur * 32768;

            if (li < 2) {                        // init temp acc with bias
                const float* bb = (li == 0 ? b1 : b2) + d * HD;
                #pragma unroll
                for (int tm = 0; tm < 8; ++tm) {
                    const f32x4 bv = *(const f32x4*)(bb + tm * 16 + g * 4);
                    #pragma unroll
                    for (int tc = 0; tc < 2; ++tc) acct[tm][tc] = bv;
                }
            }

            #pragma unroll
            for (int kb = 0; kb < 4; ++kb) {
                short8 afr[8];
                #pragma unroll
                for (int tm = 0; tm < 8; ++tm)
                    afr[tm] = *reinterpret_cast<const short8*>(
                        wbase + (kb * 8 + tm) * 1024 + lane * 16);
                #pragma unroll
                for (int tm = 0; tm < 8; ++tm)
                    #pragma unroll
                    for (int tc = 0; tc < 2; ++tc) {
                        if (li < 2)
                            acct[tm][tc] = __builtin_amdgcn_mfma_f32_16x16x32_bf16(
                                afr[tm], bfrag[kb][tc], acct[tm][tc], 0, 0, 0);
                        else
                            acc3[tm][tc] = __builtin_amdgcn_mfma_f32_16x16x32_bf16(
                                afr[tm], bfrag[kb][tc], acc3[tm][tc], 0, 0, 0);
                    }
            }

            // layer output -> next B-fragments (in-register; K-permutation
            // makes D layout == B layout). Mask folded into h2 before layer 3.
            if (li < 2) {
                #pragma unroll
                for (int kb = 0; kb < 4; ++kb)
                    #pragma unroll
                    for (int tc = 0; tc < 2; ++tc) {
                        short8 f;
                        #pragma unroll
                        for (int q = 0; q < 4; ++q) {
                            float va = fmaxf(acct[2 * kb][tc][q], 0.f);
                            float vb = fmaxf(acct[2 * kb + 1][tc][q], 0.f);
                            if (li == 1) { va *= mkf[tc]; vb *= mkf[tc]; }
                            f[q]     = bf16_bits(va);
                            f[4 + q] = bf16_bits(vb);
                        }
                        bfrag[kb][tc] = f;
                    }
            }
            cur ^= 1;
        }
    }

    // ---- epilogue: + sum_d mask_d * b3_d, store fp32 float4 ----
    #pragma unroll
    for (int tc = 0; tc < 2; ++tc) {
        const int row = row0 + tc * 16 + r;
        float mk[3];
        #pragma unroll
        for (int dd = 0; dd < 3; ++dd) {
            const int mi = row * 3 + dd;
            mk[dd] = (bytewise ? (mask_b[mi] != 0) : (mask_w[mi] != 0)) ? 1.f : 0.f;
        }
        float* orow = out + (long)row * HD;
        #pragma unroll
        for (int tm = 0; tm < 8; ++tm) {
            const f32x4 ba  = *(const f32x4*)(b3 + 0 * HD + tm * 16 + g * 4);
            const f32x4 bbv = *(const f32x4*)(b3 + 1 * HD + tm * 16 + g * 4);
            const f32x4 bc  = *(const f32x4*)(b3 + 2 * HD + tm * 16 + g * 4);
            f32x4 o = acc3[tm][tc];
            #pragma unroll
            for (int q = 0; q < 4; ++q)
                o[q] += mk[0] * ba[q] + mk[1] * bbv[q] + mk[2] * bc[q];
            *reinterpret_cast<f32x4*>(orow + tm * 16 + g * 4) = o;
        }
    }
}

extern "C" void kernel_launch(void* const* d_in, const int* in_sizes, int n_in,
                              void* d_out, int out_size, void* d_ws, size_t ws_size,
                              hipStream_t stream) {
    const float* x  = (const float*)d_in[0];
    const unsigned char* mask = (const unsigned char*)d_in[1];
    const float* W0 = (const float*)d_in[2];
    const float* b0 = (const float*)d_in[3];
    const float* W1 = (const float*)d_in[4];
    const float* b1 = (const float*)d_in[5];
    const float* W2 = (const float*)d_in[6];
    const float* b2 = (const float*)d_in[7];
    const float* W3 = (const float*)d_in[8];
    const float* b3 = (const float*)d_in[9];
    float* out = (float*)d_out;
    char* ws = (char*)d_ws;               // weights: 9*32768 B, flag at +294912
    int* mflag = (int*)(ws + 9 * 32768);
    const int n_mask = in_sizes[1];       // N*D elements

    hipLaunchKernelGGL(detect_mask_kernel, dim3(1), dim3(256), 0, stream,
                       mask, n_mask, mflag);
    hipLaunchKernelGGL(precast_kernel, dim3(9, 8), dim3(256), 0, stream, W1, W2, W3, ws);
    hipLaunchKernelGGL(mlp_kernel, dim3(1024), dim3(256), 0, stream,
                       x, (const void*)mask, mflag, W0, b0, b1, b2, b3, ws, out);
}